// Round 8
// baseline (323.302 us; speedup 1.0000x reference)
//
#include <hip/hip_runtime.h>
#include <stdint.h>

// RBF kernel matrix: out[i,j] = exp(-gamma * max(||x_i||^2 + ||y_j||^2 - 2 x_i.y_j, 0))
// N=M=8192, D=256, fp32 in/out.
//
// R8: LDS-free GEMM. xb+yb are 4 MB fp8 total — fully L2/L3 resident — and
// the MFMA fragment pattern (lane m = lane&15 reads 32 B at 256 B row
// stride; 4 lanes cover one full 128 B line) coalesces perfectly as a
// GLOBAL load. So fragments go global->VGPR directly: zero __syncthreads,
// zero barrier vmcnt(0) drains, zero staging instructions — the structural
// stall of the m97-lineage loop (R1-R7) is removed, and the compiler is
// free to software-pipeline loads across MFMA with fine-grained vmcnt.
// Epilogue keeps R7's role-swapped float4 stores.

typedef __attribute__((ext_vector_type(4))) float f32x4;
typedef __attribute__((ext_vector_type(8))) int   i32x8;

#define NN 8192
#define MM 8192
#define DD 256   // elements per row; fp8 row = 256 bytes

// ---------------------------------------------------------------------------
// Prep: per-row squared norm (fp32) + fp8-e4m3 conversion of x and y.
// One wave per row: 64 lanes x float4 = 256 elements -> 4 fp8 bytes/lane.
// ---------------------------------------------------------------------------
__global__ __launch_bounds__(256) void prep_kernel(
    const float* __restrict__ x, const float* __restrict__ y,
    unsigned char* __restrict__ xb, unsigned char* __restrict__ yb,
    float* __restrict__ xsq, float* __restrict__ ysq) {
  const int lane = threadIdx.x & 63;
  const int row  = blockIdx.x * 4 + (threadIdx.x >> 6);  // 4 waves/block

  const float* src = x;
  unsigned char* dst = xb;
  float* sq = xsq;
  int r = row;
  if (row >= NN) { src = y; dst = yb; sq = ysq; r = row - NN; }

  const float4 v = reinterpret_cast<const float4*>(src + (size_t)r * DD)[lane];
  float s = v.x * v.x + v.y * v.y + v.z * v.z + v.w * v.w;

  int w = 0;
  w = __builtin_amdgcn_cvt_pk_fp8_f32(v.x, v.y, w, false);  // bytes 0,1
  w = __builtin_amdgcn_cvt_pk_fp8_f32(v.z, v.w, w, true);   // bytes 2,3
  reinterpret_cast<int*>(dst + (size_t)r * DD)[lane] = w;

  #pragma unroll
  for (int o = 32; o > 0; o >>= 1) s += __shfl_down(s, o);
  if (lane == 0) sq[r] = s;
}

// ---------------------------------------------------------------------------
// GEMM + fused RBF epilogue, LDS-free. 128x128 tile / block, 4 waves in 2x2;
// each wave computes 64x64 via 4x4 grid of 16x16x128 MX-fp8 MFMA tiles,
// fragments loaded straight from global (L2-hot).
// A-side = y rows (output cols), B-side = x rows (output rows).
//
// Fragment address (per lane): row (tile + lane&15) * 256 B + kk + (lane>>4)*32.
// Per frag the wave touches 16 rows x 128 B = 16 full cachelines.
// ---------------------------------------------------------------------------
__global__ __launch_bounds__(256, 3) void rbf_gemm_kernel(
    const unsigned char* __restrict__ xb, const unsigned char* __restrict__ yb,
    const float* __restrict__ xsq, const float* __restrict__ ysq,
    const float* __restrict__ gamma, float* __restrict__ out) {
  const int tid   = threadIdx.x;
  const int lane  = tid & 63;
  const int wave  = tid >> 6;
  const int waveM = wave >> 1;  // y/col side of the 2x2 wave grid
  const int waveN = wave & 1;   // x/row side
  const int row0  = blockIdx.y * 128;  // x rows (output rows)
  const int col0  = blockIdx.x * 128;  // y rows (output cols)

  const int fm = lane & 15;
  const int g  = lane >> 4;

  const unsigned char* abase =
      yb + (size_t)(col0 + waveM * 64 + fm) * DD + g * 32;
  const unsigned char* bbase =
      xb + (size_t)(row0 + waveN * 64 + fm) * DD + g * 32;

  f32x4 acc[4][4] = {};

  #pragma unroll
  for (int kt = 0; kt < 2; ++kt) {
    const int kk = kt * 128;
    i32x8 a[4], b[4];
    #pragma unroll
    for (int i = 0; i < 4; ++i)
      a[i] = *reinterpret_cast<const i32x8*>(abase + (size_t)i * 16 * DD + kk);
    #pragma unroll
    for (int j = 0; j < 4; ++j)
      b[j] = *reinterpret_cast<const i32x8*>(bbase + (size_t)j * 16 * DD + kk);

    #pragma unroll
    for (int i = 0; i < 4; ++i)
      #pragma unroll
      for (int j = 0; j < 4; ++j)
        acc[i][j] = __builtin_amdgcn_mfma_scale_f32_16x16x128_f8f6f4(
            a[i], b[j], acc[i][j], 0, 0,           // cbsz=fp8, blgp=fp8
            0, 0x7F7F7F7F, 0, 0x7F7F7F7F);        // unit e8m0 scales
  }

  // Epilogue. D[m][n]: m = A row = output col, n = B row = output row.
  // C/D layout: n = lane&15, m = (lane>>4)*4 + reg -> each lane holds 4
  // consecutive output cols of one row: float4 stores.
  const float gm = gamma[0];
  const int rowb = row0 + waveN * 64 + (lane & 15);
  const int colq = col0 + waveM * 64 + (lane >> 4) * 4;

  float xsv[4];
  #pragma unroll
  for (int j = 0; j < 4; ++j) xsv[j] = xsq[rowb + j * 16];
  float4 ysv[4];
  #pragma unroll
  for (int i = 0; i < 4; ++i)
    ysv[i] = *reinterpret_cast<const float4*>(ysq + colq + i * 16);

  #pragma unroll
  for (int j = 0; j < 4; ++j) {
    const size_t obase = (size_t)(rowb + j * 16) * MM;
    #pragma unroll
    for (int i = 0; i < 4; ++i) {
      float4 v;
      float s;
      s = xsv[j] + ysv[i].x - 2.0f * acc[i][j][0]; v.x = __expf(-gm * fmaxf(s, 0.0f));
      s = xsv[j] + ysv[i].y - 2.0f * acc[i][j][1]; v.y = __expf(-gm * fmaxf(s, 0.0f));
      s = xsv[j] + ysv[i].z - 2.0f * acc[i][j][2]; v.z = __expf(-gm * fmaxf(s, 0.0f));
      s = xsv[j] + ysv[i].w - 2.0f * acc[i][j][3]; v.w = __expf(-gm * fmaxf(s, 0.0f));
      *reinterpret_cast<float4*>(out + obase + colq + i * 16) = v;
    }
  }
}

// ---------------------------------------------------------------------------
extern "C" void kernel_launch(void* const* d_in, const int* in_sizes, int n_in,
                              void* d_out, int out_size, void* d_ws, size_t ws_size,
                              hipStream_t stream) {
  const float* x     = (const float*)d_in[0];
  const float* y     = (const float*)d_in[1];
  const float* gamma = (const float*)d_in[2];
  float* out = (float*)d_out;

  // Workspace: xb[N*256 B] fp8 | yb[M*256 B] fp8 | xsq[N] f32 | ysq[M] f32
  unsigned char* xb = (unsigned char*)d_ws;
  unsigned char* yb = xb + (size_t)NN * DD;
  float* xsq = (float*)(yb + (size_t)MM * DD);
  float* ysq = xsq + NN;

  prep_kernel<<<(NN + MM) / 4, 256, 0, stream>>>(x, y, xb, yb, xsq, ysq);

  dim3 grid(MM / 128, NN / 128);
  rbf_gemm_kernel<<<grid, 256, 0, stream>>>(xb, yb, xsq, ysq, gamma, out);
}

// Round 9
// 293.859 us; speedup vs baseline: 1.1002x; 1.1002x over previous
//
#include <hip/hip_runtime.h>
#include <stdint.h>

// RBF kernel matrix: out[i,j] = exp(-gamma * max(||x_i||^2 + ||y_j||^2 - 2 x_i.y_j, 0))
// N=M=8192, D=256, fp32 in/out.
//
// R9: R7 structure (global_load_lds staging, MX-fp8 K=128 MFMA, role-swapped
// float4 epilogue) restructured for drain overlap. R8 proved fragments must
// come via LDS (global-direct = 95 us); R7's gap vs the 43 us write floor is
// ~20 us of cold vmcnt(0) drains at barriers. Each block now does TWO
// col-adjacent 128x128 tiles sharing the x-side: Bs staged once (full K),
// As double-buffered; every A-stage is issued one phase early so its drain
// overlaps the previous compute/epilogue. 1 cold drain per block (was 4),
// 25% fewer staged bytes per output byte.

typedef __attribute__((ext_vector_type(4))) float f32x4;
typedef __attribute__((ext_vector_type(8))) int   i32x8;

#define NN 8192
#define MM 8192
#define DD 256   // elements per row; fp8 row = 256 bytes
#define BK 128

// ---------------------------------------------------------------------------
// Prep: per-row squared norm (fp32) + fp8-e4m3 conversion of x and y.
// ---------------------------------------------------------------------------
__global__ __launch_bounds__(256) void prep_kernel(
    const float* __restrict__ x, const float* __restrict__ y,
    unsigned char* __restrict__ xb, unsigned char* __restrict__ yb,
    float* __restrict__ xsq, float* __restrict__ ysq) {
  const int lane = threadIdx.x & 63;
  const int row  = blockIdx.x * 4 + (threadIdx.x >> 6);  // 4 waves/block

  const float* src = x;
  unsigned char* dst = xb;
  float* sq = xsq;
  int r = row;
  if (row >= NN) { src = y; dst = yb; sq = ysq; r = row - NN; }

  const float4 v = reinterpret_cast<const float4*>(src + (size_t)r * DD)[lane];
  float s = v.x * v.x + v.y * v.y + v.z * v.z + v.w * v.w;

  int w = 0;
  w = __builtin_amdgcn_cvt_pk_fp8_f32(v.x, v.y, w, false);  // bytes 0,1
  w = __builtin_amdgcn_cvt_pk_fp8_f32(v.z, v.w, w, true);   // bytes 2,3
  reinterpret_cast<int*>(dst + (size_t)r * DD)[lane] = w;

  #pragma unroll
  for (int o = 32; o > 0; o >>= 1) s += __shfl_down(s, o);
  if (lane == 0) sq[r] = s;
}

// ---------------------------------------------------------------------------
// GEMM + fused RBF epilogue. Block = 128 x-rows x 256 y-cols (two 128x128
// tiles t0/t1), 4 waves in 2x2 per tile. Bs = x-side full K (32 KB, staged
// once); As = y-side double buffer (2 x 16 KB).
// Swizzle (R7): 16 B seg s of row r at position (s&1) | (((s>>1)^(r&3))<<1);
// fragments are 32 B contiguous at fm*128 + (g^(fm&3))*32.
// ---------------------------------------------------------------------------
__global__ __launch_bounds__(256, 2) void rbf_gemm_kernel(
    const unsigned char* __restrict__ xb, const unsigned char* __restrict__ yb,
    const float* __restrict__ xsq, const float* __restrict__ ysq,
    const float* __restrict__ gamma, float* __restrict__ out) {
  __shared__ unsigned char Bs[2 * 128 * BK];   // x side, full K: 32 KB
  __shared__ unsigned char As[2][128 * BK];    // y side, dbuf: 2 x 16 KB

  const int tid   = threadIdx.x;
  const int lane  = tid & 63;
  const int wave  = tid >> 6;
  const int waveM = wave >> 1;  // y/col side of the 2x2 wave grid
  const int waveN = wave & 1;   // x/row side
  const int row0  = blockIdx.y * 128;  // x rows (output rows)
  const int col0  = blockIdx.x * 256;  // y rows (output cols), two tiles

  // Staging geometry (R7): issue p of chunk c covers LDS slots [p*64,+64);
  // lane -> row r = p*8 + (lane>>3), slot pos = lane&7.
  const int srow = lane >> 3;
  const int spos = lane & 7;
  const int sseg = ((spos & 1) | (((spos >> 1) ^ (srow & 3)) << 1)) * 16;

  // Fragment geometry (R7).
  const int fm = lane & 15;
  const int g  = lane >> 4;
  const int foff = fm * 128 + ((g ^ (fm & 3)) * 32);

  auto stageA = [&](unsigned char* dstbuf, int colt, int kk) {
    #pragma unroll
    for (int q = 0; q < 2; ++q) {
      const int c = wave * 2 + q;
      #pragma unroll
      for (int p = 0; p < 2; ++p) {
        const unsigned char* ga =
            yb + (size_t)(col0 + colt + c * 16 + p * 8 + srow) * DD + kk + sseg;
        __builtin_amdgcn_global_load_lds(
            (const __attribute__((address_space(1))) void*)ga,
            (__attribute__((address_space(3))) void*)(dstbuf + c * 2048 + p * 1024),
            16, 0, 0);
      }
    }
  };
  auto stageB = [&](int kt) {
    #pragma unroll
    for (int q = 0; q < 2; ++q) {
      const int c = wave * 2 + q;
      #pragma unroll
      for (int p = 0; p < 2; ++p) {
        const unsigned char* gb =
            xb + (size_t)(row0 + c * 16 + p * 8 + srow) * DD + kt * BK + sseg;
        __builtin_amdgcn_global_load_lds(
            (const __attribute__((address_space(1))) void*)gb,
            (__attribute__((address_space(3))) void*)(Bs + kt * 16384 + c * 2048 + p * 1024),
            16, 0, 0);
      }
    }
  };
  auto compute = [&](f32x4 (&acc)[4][4], const unsigned char* Abase, int kt) {
    i32x8 a[4], b[4];
    const unsigned char* Bbase = Bs + kt * 16384;
    #pragma unroll
    for (int i = 0; i < 4; ++i)
      a[i] = *reinterpret_cast<const i32x8*>(Abase + (waveM * 4 + i) * 2048 + foff);
    #pragma unroll
    for (int j = 0; j < 4; ++j)
      b[j] = *reinterpret_cast<const i32x8*>(Bbase + (waveN * 4 + j) * 2048 + foff);
    #pragma unroll
    for (int i = 0; i < 4; ++i)
      #pragma unroll
      for (int j = 0; j < 4; ++j)
        acc[i][j] = __builtin_amdgcn_mfma_scale_f32_16x16x128_f8f6f4(
            a[i], b[j], acc[i][j], 0, 0,       // cbsz=fp8, blgp=fp8
            0, 0x7F7F7F7F, 0, 0x7F7F7F7F);    // unit e8m0 scales
  };
  const float gm = gamma[0];
  auto epilogue = [&](const f32x4 (&acc)[4][4], int col0t) {
    const int rowb = row0 + waveN * 64 + (lane & 15);
    const int colq = col0t + waveM * 64 + (lane >> 4) * 4;
    float xsv[4];
    #pragma unroll
    for (int j = 0; j < 4; ++j) xsv[j] = xsq[rowb + j * 16];
    float4 ysv[4];
    #pragma unroll
    for (int i = 0; i < 4; ++i)
      ysv[i] = *reinterpret_cast<const float4*>(ysq + colq + i * 16);
    #pragma unroll
    for (int j = 0; j < 4; ++j) {
      const size_t obase = (size_t)(rowb + j * 16) * MM;
      #pragma unroll
      for (int i = 0; i < 4; ++i) {
        float4 v;
        float s;
        s = xsv[j] + ysv[i].x - 2.0f * acc[i][j][0]; v.x = __expf(-gm * fmaxf(s, 0.0f));
        s = xsv[j] + ysv[i].y - 2.0f * acc[i][j][1]; v.y = __expf(-gm * fmaxf(s, 0.0f));
        s = xsv[j] + ysv[i].z - 2.0f * acc[i][j][2]; v.z = __expf(-gm * fmaxf(s, 0.0f));
        s = xsv[j] + ysv[i].w - 2.0f * acc[i][j][3]; v.w = __expf(-gm * fmaxf(s, 0.0f));
        *reinterpret_cast<float4*>(out + obase + colq + i * 16) = v;
      }
    }
  };

  f32x4 acc0[4][4] = {};
  f32x4 acc1[4][4] = {};

  // Phase 0: B full-K + A(t0,k0); the only cold drain.
  stageB(0); stageB(1);
  stageA(As[0], 0, 0);
  __syncthreads();                       // cold drain

  stageA(As[1], 0, BK);                  // prefetch t0k1
  compute(acc0, As[0], 0);
  __syncthreads();                       // drains t0k1 (overlapped by compute)

  stageA(As[0], 128, 0);                 // prefetch t1k0 (buf0's reads done)
  compute(acc0, As[1], 1);
  __syncthreads();                       // drains t1k0 (overlapped)

  stageA(As[1], 128, BK);                // prefetch t1k1 (buf1's reads done)
  compute(acc1, As[0], 0);
  epilogue(acc0, col0);                  // t0 stores overlap t1k1's flight
  __syncthreads();                       // drains t1k1 (overlapped)

  compute(acc1, As[1], 1);
  epilogue(acc1, col0 + 128);
}

// ---------------------------------------------------------------------------
extern "C" void kernel_launch(void* const* d_in, const int* in_sizes, int n_in,
                              void* d_out, int out_size, void* d_ws, size_t ws_size,
                              hipStream_t stream) {
  const float* x     = (const float*)d_in[0];
  const float* y     = (const float*)d_in[1];
  const float* gamma = (const float*)d_in[2];
  float* out = (float*)d_out;

  // Workspace: xb[N*256 B] fp8 | yb[M*256 B] fp8 | xsq[N] f32 | ysq[M] f32
  unsigned char* xb = (unsigned char*)d_ws;
  unsigned char* yb = xb + (size_t)NN * DD;
  float* xsq = (float*)(yb + (size_t)MM * DD);
  float* ysq = xsq + NN;

  prep_kernel<<<(NN + MM) / 4, 256, 0, stream>>>(x, y, xb, yb, xsq, ysq);

  dim3 grid(MM / 256, NN / 128);  // 32 x 64 = 2048 blocks, 2 tiles each
  rbf_gemm_kernel<<<grid, 256, 0, stream>>>(xb, yb, xsq, ysq, gamma, out);
}

// Round 10
// 291.469 us; speedup vs baseline: 1.1092x; 1.0082x over previous
//
#include <hip/hip_runtime.h>
#include <stdint.h>

// RBF kernel matrix: out[i,j] = exp(-gamma * max(||x_i||^2 + ||y_j||^2 - 2 x_i.y_j, 0))
// N=M=8192, D=256, fp32 in/out.
//
// R10: exact R7 kernel (global_load_lds staging, pair-preserving XOR swizzle,
// MX-fp8 K=128 MFMA, role-swapped float4 epilogue) with occupancy 2 -> 3
// blocks/CU (__launch_bounds__(256,3), VGPR cap 168). R9 showed intra-block
// drain scheduling is not the lever; the residual ~14 us over the 43 us HBM
// write floor is store-burst serialization between near-lockstep blocks.
// A third independent block per CU desynchronizes epilogue bursts vs K-loops.

typedef __attribute__((ext_vector_type(4))) float f32x4;
typedef __attribute__((ext_vector_type(8))) int   i32x8;

#define NN 8192
#define MM 8192
#define DD 256   // elements per row; fp8 row = 256 bytes
#define BK 128

// ---------------------------------------------------------------------------
// Prep: per-row squared norm (fp32) + fp8-e4m3 conversion of x and y.
// ---------------------------------------------------------------------------
__global__ __launch_bounds__(256) void prep_kernel(
    const float* __restrict__ x, const float* __restrict__ y,
    unsigned char* __restrict__ xb, unsigned char* __restrict__ yb,
    float* __restrict__ xsq, float* __restrict__ ysq) {
  const int lane = threadIdx.x & 63;
  const int row  = blockIdx.x * 4 + (threadIdx.x >> 6);  // 4 waves/block

  const float* src = x;
  unsigned char* dst = xb;
  float* sq = xsq;
  int r = row;
  if (row >= NN) { src = y; dst = yb; sq = ysq; r = row - NN; }

  const float4 v = reinterpret_cast<const float4*>(src + (size_t)r * DD)[lane];
  float s = v.x * v.x + v.y * v.y + v.z * v.z + v.w * v.w;

  int w = 0;
  w = __builtin_amdgcn_cvt_pk_fp8_f32(v.x, v.y, w, false);  // bytes 0,1
  w = __builtin_amdgcn_cvt_pk_fp8_f32(v.z, v.w, w, true);   // bytes 2,3
  reinterpret_cast<int*>(dst + (size_t)r * DD)[lane] = w;

  #pragma unroll
  for (int o = 32; o > 0; o >>= 1) s += __shfl_down(s, o);
  if (lane == 0) sq[r] = s;
}

// ---------------------------------------------------------------------------
// GEMM + fused RBF epilogue. 128x128 tile / block, 4 waves in 2x2; each wave
// 64x64 via 4x4 grid of 16x16x128 MX-fp8 MFMA tiles, 2 K-iters (BK=128).
// A-side = y rows (output cols), B-side = x rows (output rows).
//
// LDS chunk c (2 KiB) = rows [c*16,c*16+16) x K-window [kk,kk+128) fp8.
// Pair-preserving swizzle: 16 B seg s of row r stored at position
// (s&1) | (((s>>1) ^ (r&3)) << 1)  -> 32 B fragment windows stay contiguous.
// ---------------------------------------------------------------------------
__global__ __launch_bounds__(256, 3) void rbf_gemm_kernel(
    const unsigned char* __restrict__ xb, const unsigned char* __restrict__ yb,
    const float* __restrict__ xsq, const float* __restrict__ ysq,
    const float* __restrict__ gamma, float* __restrict__ out) {
  __shared__ unsigned char As[128 * BK];  // y side (output cols), 16 KB
  __shared__ unsigned char Bs[128 * BK];  // x side (output rows), 16 KB

  const int tid   = threadIdx.x;
  const int lane  = tid & 63;
  const int wave  = tid >> 6;
  const int waveM = wave >> 1;  // y/col side of the 2x2 wave grid
  const int waveN = wave & 1;   // x/row side
  const int row0  = blockIdx.y * 128;  // x rows (output rows)
  const int col0  = blockIdx.x * 128;  // y rows (output cols)

  f32x4 acc[4][4] = {};

  // Staging: issue p of chunk c covers LDS slots [p*64, p*64+64) (16 B each);
  // lane -> row r = p*8 + (lane>>3), slot pos = lane&7, global seg
  // s = (pos&1) | (((pos>>1) ^ (r&3)) << 1). 8-lane groups cover one 128 B
  // global run (segs permuted) -> coalesced.
  const int srow = lane >> 3;
  const int spos = lane & 7;
  const int sseg = ((spos & 1) | (((spos >> 1) ^ (srow & 3)) << 1)) * 16;

  // Fragment: fm = lane&15 (matrix row), g = lane>>4 (32 B k-window).
  // Window g of row fm lives at byte offset fm*128 + (g^(fm&3))*32, 32 B
  // contiguous -> one i32x8 load (2x ds_read_b128, 2-way banking = free).
  const int fm = lane & 15;
  const int g  = lane >> 4;
  const int foff = fm * 128 + ((g ^ (fm & 3)) * 32);

  #pragma unroll
  for (int kt = 0; kt < 2; ++kt) {
    const int kk = kt * BK;
    __syncthreads();  // previous iteration's ds_reads done before overwrite
    #pragma unroll
    for (int q = 0; q < 2; ++q) {
      const int c = wave * 2 + q;  // wave-uniform chunk id, 8 chunks = 128 rows
      #pragma unroll
      for (int p = 0; p < 2; ++p) {
        const unsigned char* ga =
            yb + (size_t)(col0 + c * 16 + p * 8 + srow) * DD + kk + sseg;
        __builtin_amdgcn_global_load_lds(
            (const __attribute__((address_space(1))) void*)ga,
            (__attribute__((address_space(3))) void*)(As + c * 2048 + p * 1024),
            16, 0, 0);
        const unsigned char* gb =
            xb + (size_t)(row0 + c * 16 + p * 8 + srow) * DD + kk + sseg;
        __builtin_amdgcn_global_load_lds(
            (const __attribute__((address_space(1))) void*)gb,
            (__attribute__((address_space(3))) void*)(Bs + c * 2048 + p * 1024),
            16, 0, 0);
      }
    }
    __syncthreads();  // staging complete

    i32x8 a[4], b[4];
    #pragma unroll
    for (int i = 0; i < 4; ++i)
      a[i] = *reinterpret_cast<const i32x8*>(As + (waveM * 4 + i) * 2048 + foff);
    #pragma unroll
    for (int j = 0; j < 4; ++j)
      b[j] = *reinterpret_cast<const i32x8*>(Bs + (waveN * 4 + j) * 2048 + foff);

    #pragma unroll
    for (int i = 0; i < 4; ++i)
      #pragma unroll
      for (int j = 0; j < 4; ++j)
        acc[i][j] = __builtin_amdgcn_mfma_scale_f32_16x16x128_f8f6f4(
            a[i], b[j], acc[i][j], 0, 0,           // cbsz=fp8, blgp=fp8
            0, 0x7F7F7F7F, 0, 0x7F7F7F7F);        // unit e8m0 scales
  }

  // Epilogue. D[m][n]: m = A row = output col, n = B row = output row.
  // C/D layout: n = lane&15, m = (lane>>4)*4 + reg  ->  each lane holds 4
  // consecutive output cols of one row: float4 stores, full 64 B runs/row.
  const float gm = gamma[0];
  const int rowb = row0 + waveN * 64 + (lane & 15);
  const int colq = col0 + waveM * 64 + (lane >> 4) * 4;

  float xsv[4];
  #pragma unroll
  for (int j = 0; j < 4; ++j) xsv[j] = xsq[rowb + j * 16];
  float4 ysv[4];
  #pragma unroll
  for (int i = 0; i < 4; ++i)
    ysv[i] = *reinterpret_cast<const float4*>(ysq + colq + i * 16);

  #pragma unroll
  for (int j = 0; j < 4; ++j) {
    const size_t obase = (size_t)(rowb + j * 16) * MM;
    #pragma unroll
    for (int i = 0; i < 4; ++i) {
      float4 v;
      float s;
      s = xsv[j] + ysv[i].x - 2.0f * acc[i][j][0]; v.x = __expf(-gm * fmaxf(s, 0.0f));
      s = xsv[j] + ysv[i].y - 2.0f * acc[i][j][1]; v.y = __expf(-gm * fmaxf(s, 0.0f));
      s = xsv[j] + ysv[i].z - 2.0f * acc[i][j][2]; v.z = __expf(-gm * fmaxf(s, 0.0f));
      s = xsv[j] + ysv[i].w - 2.0f * acc[i][j][3]; v.w = __expf(-gm * fmaxf(s, 0.0f));
      *reinterpret_cast<float4*>(out + obase + colq + i * 16) = v;
    }
  }
}

// ---------------------------------------------------------------------------
extern "C" void kernel_launch(void* const* d_in, const int* in_sizes, int n_in,
                              void* d_out, int out_size, void* d_ws, size_t ws_size,
                              hipStream_t stream) {
  const float* x     = (const float*)d_in[0];
  const float* y     = (const float*)d_in[1];
  const float* gamma = (const float*)d_in[2];
  float* out = (float*)d_out;

  // Workspace: xb[N*256 B] fp8 | yb[M*256 B] fp8 | xsq[N] f32 | ysq[M] f32
  unsigned char* xb = (unsigned char*)d_ws;
  unsigned char* yb = xb + (size_t)NN * DD;
  float* xsq = (float*)(yb + (size_t)MM * DD);
  float* ysq = xsq + NN;

  prep_kernel<<<(NN + MM) / 4, 256, 0, stream>>>(x, y, xb, yb, xsq, ysq);

  dim3 grid(MM / 128, NN / 128);
  rbf_gemm_kernel<<<grid, 256, 0, stream>>>(xb, yb, xsq, ysq, gamma, out);
}

// Round 11
// 287.145 us; speedup vs baseline: 1.1259x; 1.0151x over previous
//
#include <hip/hip_runtime.h>
#include <stdint.h>

// RBF kernel matrix: out[i,j] = exp(-gamma * max(||x_i||^2 + ||y_j||^2 - 2 x_i.y_j, 0))
// N=M=8192, D=256, fp32 in/out.
//
// R11: R7 structure (best measured: global_load_lds staging, pair-preserving
// XOR swizzle, MX-fp8 K=128 MFMA, role-swapped float4 epilogue, 2 blocks/CU)
// + underflow fast-path epilogue. v_exp_f32 is quarter-rate: the 64 exps per
// thread cost ~13.6 us/CU of transcendental-pipe time — the hidden residue
// over the 43 us write floor. Per float4 group: if gamma*min4(s) >= 105
// (exp < 2^-149 -> 0.0f even via denormals), store zeros and never touch the
// exp pipe; else the full __expf path (general-case correct). For N(0,I_256)
// data sqdist >= ~265 everywhere, so the fast path is wave-uniform-taken.

typedef __attribute__((ext_vector_type(4))) float f32x4;
typedef __attribute__((ext_vector_type(8))) int   i32x8;

#define NN 8192
#define MM 8192
#define DD 256   // elements per row; fp8 row = 256 bytes
#define BK 128

// ---------------------------------------------------------------------------
// Prep: per-row squared norm (fp32) + fp8-e4m3 conversion of x and y.
// ---------------------------------------------------------------------------
__global__ __launch_bounds__(256) void prep_kernel(
    const float* __restrict__ x, const float* __restrict__ y,
    unsigned char* __restrict__ xb, unsigned char* __restrict__ yb,
    float* __restrict__ xsq, float* __restrict__ ysq) {
  const int lane = threadIdx.x & 63;
  const int row  = blockIdx.x * 4 + (threadIdx.x >> 6);  // 4 waves/block

  const float* src = x;
  unsigned char* dst = xb;
  float* sq = xsq;
  int r = row;
  if (row >= NN) { src = y; dst = yb; sq = ysq; r = row - NN; }

  const float4 v = reinterpret_cast<const float4*>(src + (size_t)r * DD)[lane];
  float s = v.x * v.x + v.y * v.y + v.z * v.z + v.w * v.w;

  int w = 0;
  w = __builtin_amdgcn_cvt_pk_fp8_f32(v.x, v.y, w, false);  // bytes 0,1
  w = __builtin_amdgcn_cvt_pk_fp8_f32(v.z, v.w, w, true);   // bytes 2,3
  reinterpret_cast<int*>(dst + (size_t)r * DD)[lane] = w;

  #pragma unroll
  for (int o = 32; o > 0; o >>= 1) s += __shfl_down(s, o);
  if (lane == 0) sq[r] = s;
}

// ---------------------------------------------------------------------------
// GEMM + fused RBF epilogue. 128x128 tile / block, 4 waves in 2x2; each wave
// 64x64 via 4x4 grid of 16x16x128 MX-fp8 MFMA tiles, 2 K-iters (BK=128).
// A-side = y rows (output cols), B-side = x rows (output rows).
//
// LDS chunk c (2 KiB) = rows [c*16,c*16+16) x K-window [kk,kk+128) fp8.
// Pair-preserving swizzle: 16 B seg s of row r stored at position
// (s&1) | (((s>>1) ^ (r&3)) << 1)  -> 32 B fragment windows stay contiguous.
// ---------------------------------------------------------------------------
__global__ __launch_bounds__(256, 2) void rbf_gemm_kernel(
    const unsigned char* __restrict__ xb, const unsigned char* __restrict__ yb,
    const float* __restrict__ xsq, const float* __restrict__ ysq,
    const float* __restrict__ gamma, float* __restrict__ out) {
  __shared__ unsigned char As[128 * BK];  // y side (output cols), 16 KB
  __shared__ unsigned char Bs[128 * BK];  // x side (output rows), 16 KB

  const int tid   = threadIdx.x;
  const int lane  = tid & 63;
  const int wave  = tid >> 6;
  const int waveM = wave >> 1;  // y/col side of the 2x2 wave grid
  const int waveN = wave & 1;   // x/row side
  const int row0  = blockIdx.y * 128;  // x rows (output rows)
  const int col0  = blockIdx.x * 128;  // y rows (output cols)

  f32x4 acc[4][4] = {};

  // Staging: issue p of chunk c covers LDS slots [p*64, p*64+64) (16 B each);
  // lane -> row r = p*8 + (lane>>3), slot pos = lane&7, global seg
  // s = (pos&1) | (((pos>>1) ^ (r&3)) << 1). 8-lane groups cover one 128 B
  // global run (segs permuted) -> coalesced.
  const int srow = lane >> 3;
  const int spos = lane & 7;
  const int sseg = ((spos & 1) | (((spos >> 1) ^ (srow & 3)) << 1)) * 16;

  // Fragment: fm = lane&15 (matrix row), g = lane>>4 (32 B k-window).
  // Window g of row fm lives at byte offset fm*128 + (g^(fm&3))*32, 32 B
  // contiguous -> one i32x8 load (2x ds_read_b128, 2-way banking = free).
  const int fm = lane & 15;
  const int g  = lane >> 4;
  const int foff = fm * 128 + ((g ^ (fm & 3)) * 32);

  #pragma unroll
  for (int kt = 0; kt < 2; ++kt) {
    const int kk = kt * BK;
    __syncthreads();  // previous iteration's ds_reads done before overwrite
    #pragma unroll
    for (int q = 0; q < 2; ++q) {
      const int c = wave * 2 + q;  // wave-uniform chunk id, 8 chunks = 128 rows
      #pragma unroll
      for (int p = 0; p < 2; ++p) {
        const unsigned char* ga =
            yb + (size_t)(col0 + c * 16 + p * 8 + srow) * DD + kk + sseg;
        __builtin_amdgcn_global_load_lds(
            (const __attribute__((address_space(1))) void*)ga,
            (__attribute__((address_space(3))) void*)(As + c * 2048 + p * 1024),
            16, 0, 0);
        const unsigned char* gb =
            xb + (size_t)(row0 + c * 16 + p * 8 + srow) * DD + kk + sseg;
        __builtin_amdgcn_global_load_lds(
            (const __attribute__((address_space(1))) void*)gb,
            (__attribute__((address_space(3))) void*)(Bs + c * 2048 + p * 1024),
            16, 0, 0);
      }
    }
    __syncthreads();  // staging complete

    i32x8 a[4], b[4];
    #pragma unroll
    for (int i = 0; i < 4; ++i)
      a[i] = *reinterpret_cast<const i32x8*>(As + (waveM * 4 + i) * 2048 + foff);
    #pragma unroll
    for (int j = 0; j < 4; ++j)
      b[j] = *reinterpret_cast<const i32x8*>(Bs + (waveN * 4 + j) * 2048 + foff);

    #pragma unroll
    for (int i = 0; i < 4; ++i)
      #pragma unroll
      for (int j = 0; j < 4; ++j)
        acc[i][j] = __builtin_amdgcn_mfma_scale_f32_16x16x128_f8f6f4(
            a[i], b[j], acc[i][j], 0, 0,           // cbsz=fp8, blgp=fp8
            0, 0x7F7F7F7F, 0, 0x7F7F7F7F);        // unit e8m0 scales
  }

  // Epilogue. D[m][n]: m = A row = output col, n = B row = output row.
  // C/D layout: n = lane&15, m = (lane>>4)*4 + reg  ->  each lane holds 4
  // consecutive output cols of one row: float4 stores, full 64 B runs/row.
  const float gm = gamma[0];
  const int rowb = row0 + waveN * 64 + (lane & 15);
  const int colq = col0 + waveM * 64 + (lane >> 4) * 4;

  float xsv[4];
  #pragma unroll
  for (int j = 0; j < 4; ++j) xsv[j] = xsq[rowb + j * 16];
  float4 ysv[4];
  #pragma unroll
  for (int i = 0; i < 4; ++i)
    ysv[i] = *reinterpret_cast<const float4*>(ysq + colq + i * 16);

  #pragma unroll
  for (int j = 0; j < 4; ++j) {
    const size_t obase = (size_t)(rowb + j * 16) * MM;
    #pragma unroll
    for (int i = 0; i < 4; ++i) {
      const float s0 = xsv[j] + ysv[i].x - 2.0f * acc[i][j][0];
      const float s1 = xsv[j] + ysv[i].y - 2.0f * acc[i][j][1];
      const float s2 = xsv[j] + ysv[i].z - 2.0f * acc[i][j][2];
      const float s3 = xsv[j] + ysv[i].w - 2.0f * acc[i][j][3];
      float4 v;
      // Underflow fast path: gm*min(s) >= 105 -> exp(-gm*s) < 2^-149 -> 0.0f
      // exactly (even with denormals). Wave-uniform-taken for this data; the
      // slow path keeps the kernel correct for any input.
      const float mn = fminf(fminf(s0, s1), fminf(s2, s3));
      if (gm * mn >= 105.0f) {
        v.x = 0.0f; v.y = 0.0f; v.z = 0.0f; v.w = 0.0f;
      } else {
        v.x = __expf(-gm * fmaxf(s0, 0.0f));
        v.y = __expf(-gm * fmaxf(s1, 0.0f));
        v.z = __expf(-gm * fmaxf(s2, 0.0f));
        v.w = __expf(-gm * fmaxf(s3, 0.0f));
      }
      *reinterpret_cast<float4*>(out + obase + colq + i * 16) = v;
    }
  }
}

// ---------------------------------------------------------------------------
extern "C" void kernel_launch(void* const* d_in, const int* in_sizes, int n_in,
                              void* d_out, int out_size, void* d_ws, size_t ws_size,
                              hipStream_t stream) {
  const float* x     = (const float*)d_in[0];
  const float* y     = (const float*)d_in[1];
  const float* gamma = (const float*)d_in[2];
  float* out = (float*)d_out;

  // Workspace: xb[N*256 B] fp8 | yb[M*256 B] fp8 | xsq[N] f32 | ysq[M] f32
  unsigned char* xb = (unsigned char*)d_ws;
  unsigned char* yb = xb + (size_t)NN * DD;
  float* xsq = (float*)(yb + (size_t)MM * DD);
  float* ysq = xsq + NN;

  prep_kernel<<<(NN + MM) / 4, 256, 0, stream>>>(x, y, xb, yb, xsq, ysq);

  dim3 grid(MM / 128, NN / 128);
  rbf_gemm_kernel<<<grid, 256, 0, stream>>>(xb, yb, xsq, ysq, gamma, out);
}

// Round 12
// 280.726 us; speedup vs baseline: 1.1517x; 1.0229x over previous
//
#include <hip/hip_runtime.h>
#include <stdint.h>

// RBF kernel matrix: out[i,j] = exp(-gamma * max(||x_i||^2 + ||y_j||^2 - 2 x_i.y_j, 0))
// N=M=8192, D=256, fp32 in/out.
//
// R12: split-column epilogue. Pipe math says the GEMM should be HBM-write
// bound (6400 cyc/tile/CU) at ~43 us, but measured ~59 us = 73% write duty:
// stores burst only in the tail epilogue while phase-locked blocks leave the
// write pipe idle during K-loops. Restructure: Bs (x-side) staged full-K,
// As (y-side) in four 8 KB (half, kt) quarters. One cold sync; compute half0
// with zero intervening barriers; epilogue half0 MID-KERNEL (overlaps As-h1
// staging flight); sync; compute+store half1. 2 barriers/block (was 4),
// 1 cold drain (was 2), store bursts halved and spaced, acc regs halved.

typedef __attribute__((ext_vector_type(4))) float f32x4;
typedef __attribute__((ext_vector_type(8))) int   i32x8;

#define NN 8192
#define MM 8192
#define DD 256   // elements per row; fp8 row = 256 bytes

// ---------------------------------------------------------------------------
// Prep: per-row squared norm (fp32) + fp8-e4m3 conversion of x and y.
// ---------------------------------------------------------------------------
__global__ __launch_bounds__(256) void prep_kernel(
    const float* __restrict__ x, const float* __restrict__ y,
    unsigned char* __restrict__ xb, unsigned char* __restrict__ yb,
    float* __restrict__ xsq, float* __restrict__ ysq) {
  const int lane = threadIdx.x & 63;
  const int row  = blockIdx.x * 4 + (threadIdx.x >> 6);  // 4 waves/block

  const float* src = x;
  unsigned char* dst = xb;
  float* sq = xsq;
  int r = row;
  if (row >= NN) { src = y; dst = yb; sq = ysq; r = row - NN; }

  const float4 v = reinterpret_cast<const float4*>(src + (size_t)r * DD)[lane];
  float s = v.x * v.x + v.y * v.y + v.z * v.z + v.w * v.w;

  int w = 0;
  w = __builtin_amdgcn_cvt_pk_fp8_f32(v.x, v.y, w, false);  // bytes 0,1
  w = __builtin_amdgcn_cvt_pk_fp8_f32(v.z, v.w, w, true);   // bytes 2,3
  reinterpret_cast<int*>(dst + (size_t)r * DD)[lane] = w;

  #pragma unroll
  for (int o = 32; o > 0; o >>= 1) s += __shfl_down(s, o);
  if (lane == 0) sq[r] = s;
}

// ---------------------------------------------------------------------------
// GEMM + fused RBF epilogue. Block = 128x128 output tile, 4 waves in 2x2.
// A-side = y rows (output cols), B-side = x rows (output rows).
// Per column-half h (64 cols): wave computes 64 rows x 32 cols = acc[2][4],
// 16 MFMA (16x16x128 MX-fp8, unit scales), then stores immediately.
//
// LDS: Bs[kt][8 chunks of 2 KiB] = x rows, 32 KB total (full K).
//      As[h][kt][4 chunks of 2 KiB] = y rows, 32 KB total.
// Chunk = 16 rows x 128 B, pair-preserving swizzle (R7): 16 B seg s of row r
// at position (s&1) | (((s>>1)^(r&3))<<1); 32 B fragment windows contiguous.
// ---------------------------------------------------------------------------
__global__ __launch_bounds__(256, 2) void rbf_gemm_kernel(
    const unsigned char* __restrict__ xb, const unsigned char* __restrict__ yb,
    const float* __restrict__ xsq, const float* __restrict__ ysq,
    const float* __restrict__ gamma, float* __restrict__ out) {
  __shared__ unsigned char Bs[2][8 * 2048];     // [kt] x side, 32 KB
  __shared__ unsigned char As[2][2][4 * 2048];  // [h][kt] y side, 32 KB

  const int tid   = threadIdx.x;
  const int lane  = tid & 63;
  const int wave  = tid >> 6;
  const int waveM = wave >> 1;  // y/col side of the 2x2 wave grid
  const int waveN = wave & 1;   // x/row side
  const int row0  = blockIdx.y * 128;  // x rows (output rows)
  const int col0  = blockIdx.x * 128;  // y rows (output cols)

  // Staging geometry (R7): per 2 KiB chunk, issue p covers rows [p*8,p*8+8);
  // lane -> row r = p*8 + (lane>>3), slot pos = lane&7, global seg
  // s = (pos&1) | (((pos>>1) ^ (r&3)) << 1). 8-lane groups cover one 128 B
  // global run (segs permuted) -> coalesced.
  const int srow = lane >> 3;
  const int spos = lane & 7;
  const int sseg = ((spos & 1) | (((spos >> 1) ^ (srow & 3)) << 1)) * 16;

  // Fragment: fm = lane&15 (matrix row), g = lane>>4 (32 B k-window);
  // window g of row fm at byte fm*128 + (g^(fm&3))*32 within its chunk.
  const int fm = lane & 15;
  const int g  = lane >> 4;
  const int foff = fm * 128 + ((g ^ (fm & 3)) * 32);

  auto stageB = [&](int kt) {
    #pragma unroll
    for (int q = 0; q < 2; ++q) {
      const int c = wave * 2 + q;  // 8 chunks = 128 x rows
      #pragma unroll
      for (int p = 0; p < 2; ++p) {
        const unsigned char* gb =
            xb + (size_t)(row0 + c * 16 + p * 8 + srow) * DD + kt * 128 + sseg;
        __builtin_amdgcn_global_load_lds(
            (const __attribute__((address_space(1))) void*)gb,
            (__attribute__((address_space(3))) void*)(Bs[kt] + c * 2048 + p * 1024),
            16, 0, 0);
      }
    }
  };
  auto stageA = [&](int h, int kt) {
    const int c = wave;  // 4 chunks = 64 y rows, one per wave
    #pragma unroll
    for (int p = 0; p < 2; ++p) {
      const unsigned char* ga =
          yb + (size_t)(col0 + h * 64 + c * 16 + p * 8 + srow) * DD + kt * 128 + sseg;
      __builtin_amdgcn_global_load_lds(
          (const __attribute__((address_space(1))) void*)ga,
          (__attribute__((address_space(3))) void*)(As[h][kt] + c * 2048 + p * 1024),
          16, 0, 0);
    }
  };

  f32x4 acc[2][4];
  const float gm = gamma[0];
  const int rowb = row0 + waveN * 64 + (lane & 15);

  float xsv[4];
  #pragma unroll
  for (int j = 0; j < 4; ++j) xsv[j] = xsq[rowb + j * 16];

  auto compute = [&](int h) {
    #pragma unroll
    for (int kt = 0; kt < 2; ++kt) {
      i32x8 a[2], b[4];
      #pragma unroll
      for (int i = 0; i < 2; ++i)
        a[i] = *reinterpret_cast<const i32x8*>(
            As[h][kt] + (waveM * 2 + i) * 2048 + foff);
      #pragma unroll
      for (int j = 0; j < 4; ++j)
        b[j] = *reinterpret_cast<const i32x8*>(
            Bs[kt] + (waveN * 4 + j) * 2048 + foff);
      #pragma unroll
      for (int i = 0; i < 2; ++i)
        #pragma unroll
        for (int j = 0; j < 4; ++j)
          acc[i][j] = __builtin_amdgcn_mfma_scale_f32_16x16x128_f8f6f4(
              a[i], b[j], acc[i][j], 0, 0,       // cbsz=fp8, blgp=fp8
              0, 0x7F7F7F7F, 0, 0x7F7F7F7F);    // unit e8m0 scales
    }
  };
  auto epilogue = [&](int h) {
    const int colq = col0 + h * 64 + waveM * 32 + (lane >> 4) * 4;
    float4 ysv[2];
    #pragma unroll
    for (int i = 0; i < 2; ++i)
      ysv[i] = *reinterpret_cast<const float4*>(ysq + colq + i * 16);
    #pragma unroll
    for (int j = 0; j < 4; ++j) {
      const size_t obase = (size_t)(rowb + j * 16) * MM;
      #pragma unroll
      for (int i = 0; i < 2; ++i) {
        const float s0 = xsv[j] + ysv[i].x - 2.0f * acc[i][j][0];
        const float s1 = xsv[j] + ysv[i].y - 2.0f * acc[i][j][1];
        const float s2 = xsv[j] + ysv[i].z - 2.0f * acc[i][j][2];
        const float s3 = xsv[j] + ysv[i].w - 2.0f * acc[i][j][3];
        float4 v;
        // Underflow fast path: gm*min(s) >= 105 -> exp < 2^-149 -> 0.0f
        // exactly; wave-uniform-taken for this data, general-case correct.
        const float mn = fminf(fminf(s0, s1), fminf(s2, s3));
        if (gm * mn >= 105.0f) {
          v.x = 0.0f; v.y = 0.0f; v.z = 0.0f; v.w = 0.0f;
        } else {
          v.x = __expf(-gm * fmaxf(s0, 0.0f));
          v.y = __expf(-gm * fmaxf(s1, 0.0f));
          v.z = __expf(-gm * fmaxf(s2, 0.0f));
          v.w = __expf(-gm * fmaxf(s3, 0.0f));
        }
        *reinterpret_cast<float4*>(out + obase + colq + i * 16) = v;
      }
    }
  };

  // Phase 0: everything half0 needs + full Bs. One cold drain.
  stageB(0); stageB(1);
  stageA(0, 0); stageA(0, 1);
  __syncthreads();                     // cold drain

  stageA(1, 0); stageA(1, 1);          // h1 prefetch, in flight during h0

  #pragma unroll
  for (int i = 0; i < 2; ++i)
    #pragma unroll
    for (int j = 0; j < 4; ++j)
      acc[i][j] = f32x4{0.f, 0.f, 0.f, 0.f};
  compute(0);
  epilogue(0);                         // mid-kernel store burst

  __syncthreads();                     // drains h1 (overlapped by h0 work)

  #pragma unroll
  for (int i = 0; i < 2; ++i)
    #pragma unroll
    for (int j = 0; j < 4; ++j)
      acc[i][j] = f32x4{0.f, 0.f, 0.f, 0.f};
  compute(1);
  epilogue(1);
}

// ---------------------------------------------------------------------------
extern "C" void kernel_launch(void* const* d_in, const int* in_sizes, int n_in,
                              void* d_out, int out_size, void* d_ws, size_t ws_size,
                              hipStream_t stream) {
  const float* x     = (const float*)d_in[0];
  const float* y     = (const float*)d_in[1];
  const float* gamma = (const float*)d_in[2];
  float* out = (float*)d_out;

  // Workspace: xb[N*256 B] fp8 | yb[M*256 B] fp8 | xsq[N] f32 | ysq[M] f32
  unsigned char* xb = (unsigned char*)d_ws;
  unsigned char* yb = xb + (size_t)NN * DD;
  float* xsq = (float*)(yb + (size_t)MM * DD);
  float* ysq = xsq + NN;

  prep_kernel<<<(NN + MM) / 4, 256, 0, stream>>>(x, y, xb, yb, xsq, ysq);

  dim3 grid(MM / 128, NN / 128);
  rbf_gemm_kernel<<<grid, 256, 0, stream>>>(xb, yb, xsq, ysq, gamma, out);
}